// Round 3
// baseline (909.562 us; speedup 1.0000x reference)
//
#include <hip/hip_runtime.h>
#include <math.h>

#define Bb 256
#define Ss 200
#define Ee 64
#define Hh 128
#define Nn 5000
#define MAXN 160

__device__ __forceinline__ float wredsum(float v){
  #pragma unroll
  for (int o = 32; o; o >>= 1) v += __shfl_xor(v, o);
  return v;
}
__device__ __forceinline__ float wredmax(float v){
  #pragma unroll
  for (int o = 32; o; o >>= 1) v = fmaxf(v, __shfl_xor(v, o));
  return v;
}
__device__ __forceinline__ float sigf(float x){ return 1.f / (1.f + __expf(-x)); }
__device__ __forceinline__ float tanh_f(float x){
  float e = __expf(-2.f * fabsf(x));
  float t = (1.f - e) / (1.f + e);
  return copysignf(t, x);
}

// ---------------------------------------------------------------- K2: gather + normalize loc embeddings
__global__ void norm_gather(const float* __restrict__ loc_emb,
                            const int* __restrict__ loc1, const int* __restrict__ loc2,
                            float* __restrict__ ne1, float* __restrict__ ne2){
  int wid = blockIdx.x * 4 + (threadIdx.x >> 6);
  int lane = threadIdx.x & 63;
  const int total = Bb * Ss;
  if (wid >= 2 * total) return;
  const int* loc = (wid < total) ? loc1 : loc2;
  float* ne = (wid < total) ? ne1 : ne2;
  int r = (wid < total) ? wid : wid - total;
  int idx = loc[r];
  float v = loc_emb[(size_t)idx * Ee + lane];
  float ss = wredsum(v * v);
  ne[(size_t)r * Ee + lane] = v * rsqrtf(ss);
}

// ---------------------------------------------------------------- K1: cos matrix + masked row/col max
// lane mapping: tx = tid&15 -> cols tx+16*j ; ty = tid>>4 -> rows ty+16*i
// pad rows to 68 floats (272B, 16B aligned): bank step 4 -> only free 2-way aliasing
__global__ __launch_bounds__(256) void cosmax_kernel(const float* __restrict__ ne1,
                                                     const float* __restrict__ ne2,
                                                     const int* __restrict__ len1,
                                                     const int* __restrict__ len2,
                                                     float* __restrict__ matrix_ans){
  __shared__ __align__(16) float As[128][68];
  __shared__ __align__(16) float Bs[128][68];
  int b = blockIdx.x, tid = threadIdx.x;
  int tx = tid & 15, ty = tid >> 4;
  int L1 = len1[b], L2 = len2[b];
  const float4 zero4 = make_float4(0.f, 0.f, 0.f, 0.f);
  float lie[16];
  #pragma unroll
  for (int i = 0; i < 16; i++) lie[i] = -3.0e38f;

  for (int sc = 0; sc < 2; sc++){
    float hang[8];
    #pragma unroll
    for (int i = 0; i < 8; i++) hang[i] = -3.0e38f;
    __syncthreads();                      // prior As users (reduction reads) done
    for (int i = tid; i < 2048; i += 256){
      int r = i >> 4, kq = i & 15;
      int row = sc * 128 + r;
      float4 v = (row < Ss) ? ((const float4*)ne1)[((size_t)b * Ss + row) * 16 + kq] : zero4;
      *(float4*)&As[r][kq * 4] = v;
    }
    for (int tc = 0; tc < 2; tc++){
      __syncthreads();                    // prev tile compute done; As load visible
      for (int i = tid; i < 2048; i += 256){
        int r = i >> 4, kq = i & 15;
        int col = tc * 128 + r;
        float4 v = (col < Ss) ? ((const float4*)ne2)[((size_t)b * Ss + col) * 16 + kq] : zero4;
        *(float4*)&Bs[r][kq * 4] = v;
      }
      __syncthreads();
      float acc[8][8];
      #pragma unroll
      for (int i = 0; i < 8; i++)
        #pragma unroll
        for (int j = 0; j < 8; j++) acc[i][j] = 0.f;
      #pragma unroll 4
      for (int k4 = 0; k4 < 16; k4++){
        float4 a4[8], b4[8];
        #pragma unroll
        for (int i = 0; i < 8; i++) a4[i] = *(const float4*)&As[ty + 16 * i][k4 * 4];
        #pragma unroll
        for (int j = 0; j < 8; j++) b4[j] = *(const float4*)&Bs[tx + 16 * j][k4 * 4];
        #pragma unroll
        for (int i = 0; i < 8; i++)
          #pragma unroll
          for (int j = 0; j < 8; j++)
            acc[i][j] += a4[i].x * b4[j].x + a4[i].y * b4[j].y
                       + a4[i].z * b4[j].z + a4[i].w * b4[j].w;
      }
      #pragma unroll
      for (int j = 0; j < 8; j++){
        int col = tc * 128 + tx + 16 * j;
        bool cv = col < L2;
        #pragma unroll
        for (int i = 0; i < 8; i++){
          int row = sc * 128 + ty + 16 * i;
          float v = acc[i][j];
          if (cv) hang[i] = fmaxf(hang[i], v);
          if (row < L1) lie[tc * 8 + j] = fmaxf(lie[tc * 8 + j], v);
        }
      }
    }
    // reduce hang across tx (16 partials per row), reuse As as scratch
    __syncthreads();
    float* fl = &As[0][0];
    #pragma unroll
    for (int i = 0; i < 8; i++) fl[(ty + 16 * i) * 16 + tx] = hang[i];
    __syncthreads();
    if (tid < 128){
      float m = -3.0e38f;
      #pragma unroll
      for (int p = 0; p < 16; p++) m = fmaxf(m, fl[tid * 16 + p]);
      int row = sc * 128 + tid;
      if (row < Ss) matrix_ans[(size_t)b * 400 + row] = (row < L1) ? m : 0.f;
    }
  }
  // reduce lie across ty (16 partials per col)
  __syncthreads();
  float* fl = &As[0][0];
  #pragma unroll
  for (int i = 0; i < 16; i++){
    int tcc = i >> 3, j = i & 7;
    fl[(tcc * 128 + tx + 16 * j) * 16 + ty] = lie[i];
  }
  __syncthreads();
  {
    int t = tid;
    float m = -3.0e38f;
    #pragma unroll
    for (int p = 0; p < 16; p++) m = fmaxf(m, fl[t * 16 + p]);
    if (t < Ss) matrix_ans[(size_t)b * 400 + 200 + t] = (t < L2) ? m : 0.f;
  }
}

// ---------------------------------------------------------------- KX: xg lookup table (only 168 distinct time rows)
__global__ void xg_table(const float* __restrict__ time_emb, const float* __restrict__ Wih,
                         const float* __restrict__ bih, const float* __restrict__ bhh,
                         float* __restrict__ xgtab){
  int tt = blockIdx.x, g = threadIdx.x;  // 168 blocks x 512 threads
  __shared__ float xs[64];
  if (g < 64) xs[g] = time_emb[tt * 64 + g];
  __syncthreads();
  float acc = bih[g] + bhh[g];
  #pragma unroll
  for (int k = 0; k < 64; k++) acc += Wih[g * 64 + k] * xs[k];
  xgtab[tt * 512 + g] = acc;
}

// ---------------------------------------------------------------- K3: dual-sequence LSTM with fused time-loss.
// One block per batch item; thread g = gate 0..511 (shared by both sequences,
// Whh row cached in 128 VGPRs). Per step: matvec -> gates -> h; lanes reduce
// h.v in-wave so the time-loss never needs the 52 MB hidden-state tensor.
__global__ __launch_bounds__(512) void lstm_kernel(const float* __restrict__ xgtab,
                                                   const int* __restrict__ time_1,
                                                   const int* __restrict__ time_2,
                                                   const float* __restrict__ Whh,
                                                   const float* __restrict__ tg1,
                                                   const float* __restrict__ tg2,
                                                   const int* __restrict__ len1,
                                                   const int* __restrict__ len2,
                                                   const float* __restrict__ time_v,
                                                   const float* __restrict__ time_w,
                                                   const float* __restrict__ time_b,
                                                   float* __restrict__ hfin1,
                                                   float* __restrict__ hfin2,
                                                   float* __restrict__ perb){
  int b = blockIdx.x, g = threadIdx.x;   // g = gate index 0..511
  int lane = g & 63;
  __shared__ __align__(16) float h1s[128], h2s[128];
  __shared__ float g1s[512], g2s[512];
  __shared__ int t1s[Ss], t2s[Ss];
  __shared__ float tgs[2][Ss];
  __shared__ float red[4];
  float4 w4[32];
  #pragma unroll
  for (int k = 0; k < 32; k++) w4[k] = *(const float4*)(Whh + (size_t)g * 128 + k * 4);
  for (int i = g; i < Ss; i += 512){
    t1s[i] = time_1[b * Ss + i];
    t2s[i] = time_2[b * Ss + i];
    tgs[0][i] = (i < Ss - 1) ? tg1[b * Ss + i + 1] : 0.f;   // shifted gap
    tgs[1][i] = (i < Ss - 1) ? tg2[b * Ss + i + 1] : 0.f;
  }
  if (g < 128){ h1s[g] = 0.f; h2s[g] = 0.f; }
  int l1 = len1[b], l2 = len2[b];
  float wv = time_w[0], bbias = time_b[0];
  float iw = 1.f / wv;
  float vd = (g < 256) ? time_v[g & 127] : 0.f;
  float lacc = 0.f;                       // lanes 0/1 of wave 0: seq1/seq2 loss sums
  float c_reg = 0.f;                      // threads<128: c of seq1; 128..255: c of seq2
  __syncthreads();
  for (int t = 0; t < Ss; t++){
    float xg1 = xgtab[t1s[t] * 512 + g];
    float xg2 = xgtab[t2s[t] * 512 + g];
    // 4 independent FMA chains for ILP
    float a1a = 0.f, a1b = 0.f, a2a = 0.f, a2b = 0.f;
    #pragma unroll
    for (int k = 0; k < 32; k += 2){
      float4 ha0 = *(const float4*)&h1s[k * 4];
      float4 hb0 = *(const float4*)&h2s[k * 4];
      float4 ha1 = *(const float4*)&h1s[k * 4 + 4];
      float4 hb1 = *(const float4*)&h2s[k * 4 + 4];
      a1a += w4[k].x * ha0.x + w4[k].y * ha0.y + w4[k].z * ha0.z + w4[k].w * ha0.w;
      a2a += w4[k].x * hb0.x + w4[k].y * hb0.y + w4[k].z * hb0.z + w4[k].w * hb0.w;
      a1b += w4[k+1].x * ha1.x + w4[k+1].y * ha1.y + w4[k+1].z * ha1.z + w4[k+1].w * ha1.w;
      a2b += w4[k+1].x * hb1.x + w4[k+1].y * hb1.y + w4[k+1].z * hb1.z + w4[k+1].w * hb1.w;
    }
    g1s[g] = a1a + a1b + xg1;
    g2s[g] = a2a + a2b + xg2;
    __syncthreads();                       // BARRIER-1: gates visible
    if (g < 256){
      int d = g & 127;
      const float* gs = (g < 128) ? g1s : g2s;
      float ii = sigf(gs[d]);
      float ff = sigf(gs[128 + d]);
      float gg = tanh_f(gs[256 + d]);
      float oo = sigf(gs[384 + d]);
      float c = ff * c_reg + ii * gg;
      c_reg = c;
      float h = oo * tanh_f(c);
      if (g < 128){ h1s[d] = h; if (t == l1 - 1) hfin1[(size_t)b * 128 + d] = h; }
      else        { h2s[d] = h; if (t == l2 - 1) hfin2[(size_t)b * 128 + d] = h; }
      float r = wredsum(h * vd);           // wave0: d0-63 s1, wave1: d64-127 s1, waves2/3: s2
      if (lane == 0) red[g >> 6] = r;
    }
    __syncthreads();                       // BARRIER-2: h + red visible
    if (g < 2){
      // safe: red rewritten only after all waves pass next BARRIER-1,
      // which wave 0 reaches after executing this read.
      float p = (g == 0) ? (red[0] + red[1]) : (red[2] + red[3]);
      int L = (g == 0) ? l1 : l2;
      if (t < L - 1){
        float p2 = wv * tgs[g][t];
        lacc += p + p2 + bbias + iw * expf(p + bbias) - iw * expf(p + p2 + bbias);
      }
    }
  }
  if (g < 2) red[g] = lacc;
  __syncthreads();
  if (g == 0) perb[b] = red[0] / (float)(l1 - 1) + red[1] / (float)(l2 - 1);
}

// ---------------------------------------------------------------- G0: adjacency -> fixed-stride CSR (1% dense)
__global__ void build_csr(const float* __restrict__ adj, int* __restrict__ nbr, int* __restrict__ deg){
  int row = blockIdx.x * 4 + (threadIdx.x >> 6);
  int lane = threadIdx.x & 63;
  if (row >= Nn) return;
  const float* ar = adj + (size_t)row * Nn;
  int cnt = 0;
  for (int base = 0; base < Nn; base += 64){
    int c = base + lane;
    bool nz = (c < Nn) && (ar[c] > 0.f);
    unsigned long long m = __ballot(nz);
    if (nz){
      int pos = cnt + __popcll(m & ((1ULL << lane) - 1ULL));
      if (pos < MAXN) nbr[(size_t)row * MAXN + pos] = c;
    }
    cnt += __popcll(m);
  }
  if (lane == 0) deg[row] = (cnt > MAXN) ? MAXN : cnt;
}

// ---------------------------------------------------------------- G1: h = (x*scale) @ W ; f1 = h.a[:64]; f2 = h.a[64:]
__global__ __launch_bounds__(256) void gat_xw(const float* __restrict__ x, float scale,
                                              const float* __restrict__ W,
                                              const float* __restrict__ avec,
                                              float* __restrict__ hmat,
                                              float* __restrict__ f1, float* __restrict__ f2){
  __shared__ float Ws[64][64];
  __shared__ float as_[128];
  __shared__ float xs[4][64];
  int tid = threadIdx.x, lane = tid & 63, wid = tid >> 6;
  for (int i = tid; i < 4096; i += 256) Ws[i >> 6][i & 63] = W[i];
  if (tid < 128) as_[tid] = avec[tid];
  __syncthreads();
  int row = blockIdx.x * 4 + wid;
  xs[wid][lane] = x[(size_t)row * 64 + lane] * scale;
  float acc = 0.f;
  #pragma unroll
  for (int k = 0; k < 64; k++) acc += xs[wid][k] * Ws[k][lane];
  float p1 = wredsum(acc * as_[lane]);
  float p2 = wredsum(acc * as_[64 + lane]);
  hmat[(size_t)row * 64 + lane] = acc;
  if (lane == 0){ f1[row] = p1; f2[row] = p2; }
}

// ---------------------------------------------------------------- G2: sparse masked softmax + aggregate + elu
__global__ __launch_bounds__(256) void gat_att(const float* __restrict__ hmat,
                                               const float* __restrict__ f1,
                                               const float* __restrict__ f2,
                                               const int* __restrict__ nbr,
                                               const int* __restrict__ deg,
                                               float* __restrict__ outp, int accum){
  __shared__ int nbs[4][MAXN];
  __shared__ float attb[4][MAXN];
  int tid = threadIdx.x, lane = tid & 63, w = tid >> 6;
  int row = blockIdx.x * 4 + w;
  int d = deg[row];
  float fr = f1[row];
  float mx = -3.0e38f;
  for (int j = lane; j < d; j += 64){
    int c = nbr[(size_t)row * MAXN + j];
    nbs[w][j] = c;
    float e = fr + f2[c];
    e = (e >= 0.f) ? e : 0.2f * e;   // leaky_relu alpha=0.2
    attb[w][j] = e;
    mx = fmaxf(mx, e);
  }
  mx = wredmax(mx);
  float sum = 0.f;
  for (int j = lane; j < d; j += 64){
    float ex = __expf(attb[w][j] - mx);
    attb[w][j] = ex;
    sum += ex;
  }
  sum = wredsum(sum);
  float inv = 1.f / sum;
  float acc = 0.f;
  for (int j = 0; j < d; j++)
    acc += attb[w][j] * hmat[(size_t)nbs[w][j] * 64 + lane];
  acc *= inv;
  acc = (acc > 0.f) ? acc : expm1f(acc);   // elu
  if (accum) outp[(size_t)row * 64 + lane] += acc;
  else       outp[(size_t)row * 64 + lane] = acc;
}

// ---------------------------------------------------------------- K5: feature concat + FC + loss write
__global__ void final_fc(const float* __restrict__ matrix_ans,
                         const float* __restrict__ hfin1, const float* __restrict__ hfin2,
                         const float* __restrict__ gat_emb,
                         const int* __restrict__ u1, const int* __restrict__ u2,
                         const float* __restrict__ fc_w, const float* __restrict__ fc_b,
                         const float* __restrict__ perb, float* __restrict__ out){
  int b = blockIdx.x, lane = threadIdx.x;  // 64 threads
  int a = u1[b], c = u2[b];
  float acc0 = 0.f, acc1 = 0.f;
  for (int i = lane; i < 592; i += 64){
    float f;
    if (i < 400) f = matrix_ans[(size_t)b * 400 + i];
    else if (i < 528){
      int d = i - 400;
      f = tanhf(hfin1[(size_t)b * 128 + d] * hfin2[(size_t)b * 128 + d]);
    } else {
      int d = i - 528;
      f = tanhf(gat_emb[(size_t)a * 64 + d] * gat_emb[(size_t)c * 64 + d]);
    }
    acc0 += f * fc_w[i];
    acc1 += f * fc_w[592 + i];
  }
  acc0 = wredsum(acc0);
  acc1 = wredsum(acc1);
  if (lane == 0){
    out[b * 2]     = acc0 + fc_b[0];
    out[b * 2 + 1] = acc1 + fc_b[1];
  }
  if (b == 0){
    float ls = 0.f;
    for (int i = lane; i < 256; i += 64) ls += perb[i];
    ls = wredsum(ls);
    if (lane == 0) out[512] = -ls / 256.f;
  }
}

// ----------------------------------------------------------------
extern "C" void kernel_launch(void* const* d_in, const int* in_sizes, int n_in,
                              void* d_out, int out_size, void* d_ws, size_t ws_size,
                              hipStream_t stream){
  (void)in_sizes; (void)n_in; (void)out_size; (void)ws_size;
  const int*   u1       = (const int*)  d_in[0];
  const int*   u2       = (const int*)  d_in[1];
  const int*   len1     = (const int*)  d_in[2];
  const int*   len2     = (const int*)  d_in[3];
  const int*   loc1     = (const int*)  d_in[4];
  const int*   loc2     = (const int*)  d_in[5];
  const int*   time1    = (const int*)  d_in[6];
  const int*   time2    = (const int*)  d_in[7];
  const float* tg1      = (const float*)d_in[8];
  const float* tg2      = (const float*)d_in[9];
  const float* loc_emb  = (const float*)d_in[10];
  const float* time_emb = (const float*)d_in[11];
  const float* user_emb = (const float*)d_in[12];
  const float* gat_W    = (const float*)d_in[13];
  const float* gat_a    = (const float*)d_in[14];
  const float* gat_Wout = (const float*)d_in[15];
  const float* gat_aout = (const float*)d_in[16];
  const float* adj      = (const float*)d_in[17];
  const float* Wih      = (const float*)d_in[18];
  const float* Whh      = (const float*)d_in[19];
  const float* bih      = (const float*)d_in[20];
  const float* bhh      = (const float*)d_in[21];
  const float* time_v   = (const float*)d_in[22];
  const float* time_w   = (const float*)d_in[23];
  const float* time_b   = (const float*)d_in[24];
  const float* fc_w     = (const float*)d_in[25];
  const float* fc_b     = (const float*)d_in[26];
  float* out = (float*)d_out;

  size_t off = 0;
  auto alloc = [&](size_t nbytes) -> void* {
    void* p = (char*)d_ws + off;
    off += (nbytes + 255) & ~(size_t)255;
    return p;
  };
  float* ne1        = (float*)alloc((size_t)Bb * Ss * Ee * 4);
  float* ne2        = (float*)alloc((size_t)Bb * Ss * Ee * 4);
  float* matrix_ans = (float*)alloc((size_t)Bb * 400 * 4);
  float* xgtab      = (float*)alloc((size_t)168 * 512 * 4);
  float* hfin1      = (float*)alloc((size_t)Bb * Hh * 4);
  float* hfin2      = (float*)alloc((size_t)Bb * Hh * 4);
  float* gat_h      = (float*)alloc((size_t)Nn * 64 * 4);
  float* gat_acc    = (float*)alloc((size_t)Nn * 64 * 4);
  float* gat_emb    = (float*)alloc((size_t)Nn * 64 * 4);
  float* f1w        = (float*)alloc((size_t)Nn * 4);
  float* f2w        = (float*)alloc((size_t)Nn * 4);
  float* perb       = (float*)alloc((size_t)Bb * 4);
  int*   nbr        = (int*)  alloc((size_t)Nn * MAXN * 4);
  int*   deg        = (int*)  alloc((size_t)Nn * 4);

  // cosine-sim branch
  norm_gather<<<(2 * Bb * Ss) / 4, 256, 0, stream>>>(loc_emb, loc1, loc2, ne1, ne2);
  cosmax_kernel<<<Bb, 256, 0, stream>>>(ne1, ne2, len1, len2, matrix_ans);

  // LSTM branch (time-loss fused; only final hidden rows + perb leave the kernel)
  xg_table<<<168, 512, 0, stream>>>(time_emb, Wih, bih, bhh, xgtab);
  lstm_kernel<<<Bb, 512, 0, stream>>>(xgtab, time1, time2, Whh, tg1, tg2, len1, len2,
                                      time_v, time_w, time_b, hfin1, hfin2, perb);

  // GAT branch (sparse: softmax over non-edges underflows to exactly 0 in fp32)
  build_csr<<<Nn / 4, 256, 0, stream>>>(adj, nbr, deg);
  for (int hd = 0; hd < 3; hd++){
    gat_xw<<<Nn / 4, 256, 0, stream>>>(user_emb, 1.f, gat_W + (size_t)hd * 64 * 64,
                                       gat_a + (size_t)hd * 128, gat_h, f1w, f2w);
    gat_att<<<Nn / 4, 256, 0, stream>>>(gat_h, f1w, f2w, nbr, deg, gat_acc, hd == 0 ? 0 : 1);
  }
  gat_xw<<<Nn / 4, 256, 0, stream>>>(gat_acc, 1.f / 3.f, gat_Wout, gat_aout, gat_h, f1w, f2w);
  gat_att<<<Nn / 4, 256, 0, stream>>>(gat_h, f1w, f2w, nbr, deg, gat_emb, 0);

  // fuse + FC + loss
  final_fc<<<Bb, 64, 0, stream>>>(matrix_ans, hfin1, hfin2, gat_emb,
                                  u1, u2, fc_w, fc_b, perb, out);
}

// Round 7
// 765.083 us; speedup vs baseline: 1.1888x; 1.1888x over previous
//
#include <hip/hip_runtime.h>
#include <math.h>

#define Bb 256
#define Ss 200
#define Ee 64
#define Hh 128
#define Nn 5000
#define MAXN 160

__device__ __forceinline__ float wredsum(float v){
  #pragma unroll
  for (int o = 32; o; o >>= 1) v += __shfl_xor(v, o);
  return v;
}
__device__ __forceinline__ float wredmax(float v){
  #pragma unroll
  for (int o = 32; o; o >>= 1) v = fmaxf(v, __shfl_xor(v, o));
  return v;
}
__device__ __forceinline__ float sigf(float x){ return 1.f / (1.f + __expf(-x)); }
__device__ __forceinline__ float tanh_f(float x){
  float e = __expf(-2.f * fabsf(x));
  float t = (1.f - e) / (1.f + e);
  return copysignf(t, x);
}

// ---------------------------------------------------------------- K2: gather + normalize loc embeddings
__global__ void norm_gather(const float* __restrict__ loc_emb,
                            const int* __restrict__ loc1, const int* __restrict__ loc2,
                            float* __restrict__ ne1, float* __restrict__ ne2){
  int wid = blockIdx.x * 4 + (threadIdx.x >> 6);
  int lane = threadIdx.x & 63;
  const int total = Bb * Ss;
  if (wid >= 2 * total) return;
  const int* loc = (wid < total) ? loc1 : loc2;
  float* ne = (wid < total) ? ne1 : ne2;
  int r = (wid < total) ? wid : wid - total;
  int idx = loc[r];
  float v = loc_emb[(size_t)idx * Ee + lane];
  float ss = wredsum(v * v);
  ne[(size_t)r * Ee + lane] = v * rsqrtf(ss);
}

// ---------------------------------------------------------------- K1: cos matrix + masked row/col max
// lane mapping: tx = tid&15 -> cols tx+16*j ; ty = tid>>4 -> rows ty+16*i
// pad rows to 68 floats (272B, 16B aligned): bank step 4 -> only free 2-way aliasing
__global__ __launch_bounds__(256) void cosmax_kernel(const float* __restrict__ ne1,
                                                     const float* __restrict__ ne2,
                                                     const int* __restrict__ len1,
                                                     const int* __restrict__ len2,
                                                     float* __restrict__ matrix_ans){
  __shared__ __align__(16) float As[128][68];
  __shared__ __align__(16) float Bs[128][68];
  int b = blockIdx.x, tid = threadIdx.x;
  int tx = tid & 15, ty = tid >> 4;
  int L1 = len1[b], L2 = len2[b];
  const float4 zero4 = make_float4(0.f, 0.f, 0.f, 0.f);
  float lie[16];
  #pragma unroll
  for (int i = 0; i < 16; i++) lie[i] = -3.0e38f;

  for (int sc = 0; sc < 2; sc++){
    float hang[8];
    #pragma unroll
    for (int i = 0; i < 8; i++) hang[i] = -3.0e38f;
    __syncthreads();                      // prior As users (reduction reads) done
    for (int i = tid; i < 2048; i += 256){
      int r = i >> 4, kq = i & 15;
      int row = sc * 128 + r;
      float4 v = (row < Ss) ? ((const float4*)ne1)[((size_t)b * Ss + row) * 16 + kq] : zero4;
      *(float4*)&As[r][kq * 4] = v;
    }
    for (int tc = 0; tc < 2; tc++){
      __syncthreads();                    // prev tile compute done; As load visible
      for (int i = tid; i < 2048; i += 256){
        int r = i >> 4, kq = i & 15;
        int col = tc * 128 + r;
        float4 v = (col < Ss) ? ((const float4*)ne2)[((size_t)b * Ss + col) * 16 + kq] : zero4;
        *(float4*)&Bs[r][kq * 4] = v;
      }
      __syncthreads();
      float acc[8][8];
      #pragma unroll
      for (int i = 0; i < 8; i++)
        #pragma unroll
        for (int j = 0; j < 8; j++) acc[i][j] = 0.f;
      #pragma unroll 4
      for (int k4 = 0; k4 < 16; k4++){
        float4 a4[8], b4[8];
        #pragma unroll
        for (int i = 0; i < 8; i++) a4[i] = *(const float4*)&As[ty + 16 * i][k4 * 4];
        #pragma unroll
        for (int j = 0; j < 8; j++) b4[j] = *(const float4*)&Bs[tx + 16 * j][k4 * 4];
        #pragma unroll
        for (int i = 0; i < 8; i++)
          #pragma unroll
          for (int j = 0; j < 8; j++)
            acc[i][j] += a4[i].x * b4[j].x + a4[i].y * b4[j].y
                       + a4[i].z * b4[j].z + a4[i].w * b4[j].w;
      }
      #pragma unroll
      for (int j = 0; j < 8; j++){
        int col = tc * 128 + tx + 16 * j;
        bool cv = col < L2;
        #pragma unroll
        for (int i = 0; i < 8; i++){
          int row = sc * 128 + ty + 16 * i;
          float v = acc[i][j];
          if (cv) hang[i] = fmaxf(hang[i], v);
          if (row < L1) lie[tc * 8 + j] = fmaxf(lie[tc * 8 + j], v);
        }
      }
    }
    // reduce hang across tx (16 partials per row), reuse As as scratch
    __syncthreads();
    float* fl = &As[0][0];
    #pragma unroll
    for (int i = 0; i < 8; i++) fl[(ty + 16 * i) * 16 + tx] = hang[i];
    __syncthreads();
    if (tid < 128){
      float m = -3.0e38f;
      #pragma unroll
      for (int p = 0; p < 16; p++) m = fmaxf(m, fl[tid * 16 + p]);
      int row = sc * 128 + tid;
      if (row < Ss) matrix_ans[(size_t)b * 400 + row] = (row < L1) ? m : 0.f;
    }
  }
  // reduce lie across ty (16 partials per col)
  __syncthreads();
  float* fl = &As[0][0];
  #pragma unroll
  for (int i = 0; i < 16; i++){
    int tcc = i >> 3, j = i & 7;
    fl[(tcc * 128 + tx + 16 * j) * 16 + ty] = lie[i];
  }
  __syncthreads();
  {
    int t = tid;
    float m = -3.0e38f;
    #pragma unroll
    for (int p = 0; p < 16; p++) m = fmaxf(m, fl[t * 16 + p]);
    if (t < Ss) matrix_ans[(size_t)b * 400 + 200 + t] = (t < L2) ? m : 0.f;
  }
}

// ---------------------------------------------------------------- KX: xg lookup table (only 168 distinct time rows)
__global__ void xg_table(const float* __restrict__ time_emb, const float* __restrict__ Wih,
                         const float* __restrict__ bih, const float* __restrict__ bhh,
                         float* __restrict__ xgtab){
  int tt = blockIdx.x, g = threadIdx.x;  // 168 blocks x 512 threads
  __shared__ float xs[64];
  if (g < 64) xs[g] = time_emb[tt * 64 + g];
  __syncthreads();
  float acc = bih[g] + bhh[g];
  #pragma unroll
  for (int k = 0; k < 64; k++) acc += Wih[g * 64 + k] * xs[k];
  xgtab[tt * 512 + g] = acc;
}

// ---------------------------------------------------------------- K3: dual-sequence LSTM with fused time-loss.
// Thread layout (512 thr): kq = lane>>4 (K-quarter), ggrp = wave*16 + (lane&15),
// gates g0..g0+3 (g0 = ggrp*4). Weights: 4 gates x 32 k = 128 floats, held in
// VGPRs (launch_bounds(512,2) -> 256-VGPR cap, no spill). Partials combined
// across the 4 kq lanes via shfl_xor(16/32). h stored in 36-float-padded
// chunks so the 4 kq broadcast-groups hit disjoint LDS banks.
#define HIDX(d) ((d) + (((d) >> 5) << 2))
__global__ __launch_bounds__(512, 2) void lstm_kernel(const float* __restrict__ xgtab,
                                                      const int* __restrict__ time_1,
                                                      const int* __restrict__ time_2,
                                                      const float* __restrict__ Whh,
                                                      const float* __restrict__ tg1,
                                                      const float* __restrict__ tg2,
                                                      const int* __restrict__ len1,
                                                      const int* __restrict__ len2,
                                                      const float* __restrict__ time_v,
                                                      const float* __restrict__ time_w,
                                                      const float* __restrict__ time_b,
                                                      float* __restrict__ hfin1,
                                                      float* __restrict__ hfin2,
                                                      float* __restrict__ perb){
  int b = blockIdx.x, g = threadIdx.x;
  int lane = g & 63, wave = g >> 6;
  int kq = lane >> 4;                    // K-quarter 0..3
  int g0 = (wave * 16 + (lane & 15)) * 4; // first of this thread's 4 gates
  __shared__ __align__(16) float h1s[144], h2s[144];
  __shared__ __align__(16) float g1s[512], g2s[512];
  __shared__ int t1s[Ss], t2s[Ss];
  __shared__ float tgs[2][Ss];
  __shared__ float red[4];
  // per-thread weight block: w4[j][q] = Whh[g0+j][kq*32 + q*4 ..+3]
  float4 w4[4][8];
  #pragma unroll
  for (int j = 0; j < 4; j++)
    #pragma unroll
    for (int q = 0; q < 8; q++)
      w4[j][q] = *(const float4*)(Whh + (size_t)(g0 + j) * 128 + kq * 32 + q * 4);
  for (int i = g; i < Ss; i += 512){
    t1s[i] = time_1[b * Ss + i];
    t2s[i] = time_2[b * Ss + i];
    tgs[0][i] = (i < Ss - 1) ? tg1[b * Ss + i + 1] : 0.f;   // shifted gap
    tgs[1][i] = (i < Ss - 1) ? tg2[b * Ss + i + 1] : 0.f;
  }
  if (g < 144){ h1s[g] = 0.f; h2s[g] = 0.f; }
  int l1 = len1[b], l2 = len2[b];
  float wv = time_w[0], bbias = time_b[0];
  float iw = 1.f / wv;
  float vd = (g < 256) ? time_v[g & 127] : 0.f;
  float lacc = 0.f;                       // threads 0/1: seq1/seq2 loss sums
  float c_reg = 0.f;                      // threads<128: c of seq1; 128..255: c of seq2
  __syncthreads();
  for (int t = 0; t < Ss; t++){
    float4 xg1, xg2;
    if (kq == 0){                         // issued early; ~full matvec of latency hiding
      xg1 = *(const float4*)(xgtab + (size_t)t1s[t] * 512 + g0);
      xg2 = *(const float4*)(xgtab + (size_t)t2s[t] * 512 + g0);
    }
    float a1[4] = {0.f, 0.f, 0.f, 0.f};
    float a2[4] = {0.f, 0.f, 0.f, 0.f};
    const float4* hp1 = (const float4*)&h1s[kq * 36];
    const float4* hp2 = (const float4*)&h2s[kq * 36];
    #pragma unroll
    for (int q = 0; q < 8; q++){
      float4 hv1 = hp1[q];
      float4 hv2 = hp2[q];
      #pragma unroll
      for (int j = 0; j < 4; j++){
        a1[j] += w4[j][q].x * hv1.x + w4[j][q].y * hv1.y + w4[j][q].z * hv1.z + w4[j][q].w * hv1.w;
        a2[j] += w4[j][q].x * hv2.x + w4[j][q].y * hv2.y + w4[j][q].z * hv2.z + w4[j][q].w * hv2.w;
      }
    }
    // combine the 4 K-quarters (lanes l, l^16, l^32, l^48 share gates)
    #pragma unroll
    for (int j = 0; j < 4; j++){
      a1[j] += __shfl_xor(a1[j], 16); a1[j] += __shfl_xor(a1[j], 32);
      a2[j] += __shfl_xor(a2[j], 16); a2[j] += __shfl_xor(a2[j], 32);
    }
    if (kq == 0){
      float4 o1 = make_float4(a1[0] + xg1.x, a1[1] + xg1.y, a1[2] + xg1.z, a1[3] + xg1.w);
      float4 o2 = make_float4(a2[0] + xg2.x, a2[1] + xg2.y, a2[2] + xg2.z, a2[3] + xg2.w);
      *(float4*)&g1s[g0] = o1;
      *(float4*)&g2s[g0] = o2;
    }
    __syncthreads();                       // BARRIER-1: gates visible
    if (g < 256){
      int d = g & 127;
      const float* gs = (g < 128) ? g1s : g2s;
      float ii = sigf(gs[d]);
      float ff = sigf(gs[128 + d]);
      float gg = tanh_f(gs[256 + d]);
      float oo = sigf(gs[384 + d]);
      float c = ff * c_reg + ii * gg;
      c_reg = c;
      float h = oo * tanh_f(c);
      if (g < 128){ h1s[HIDX(d)] = h; if (t == l1 - 1) hfin1[(size_t)b * 128 + d] = h; }
      else        { h2s[HIDX(d)] = h; if (t == l2 - 1) hfin2[(size_t)b * 128 + d] = h; }
      float r = wredsum(h * vd);           // wave0: d0-63 s1, wave1: d64-127 s1, waves2/3: s2
      if (lane == 0) red[g >> 6] = r;
    }
    __syncthreads();                       // BARRIER-2: h + red visible
    if (g < 2){
      // safe: red rewritten only after all waves pass next BARRIER-1,
      // which wave 0 reaches after executing this read.
      float p = (g == 0) ? (red[0] + red[1]) : (red[2] + red[3]);
      int L = (g == 0) ? l1 : l2;
      if (t < L - 1){
        float p2 = wv * tgs[g][t];
        lacc += p + p2 + bbias + iw * expf(p + bbias) - iw * expf(p + p2 + bbias);
      }
    }
  }
  if (g < 2) red[g] = lacc;
  __syncthreads();
  if (g == 0) perb[b] = red[0] / (float)(l1 - 1) + red[1] / (float)(l2 - 1);
}

// ---------------------------------------------------------------- G0: adjacency -> fixed-stride CSR (1% dense)
__global__ void build_csr(const float* __restrict__ adj, int* __restrict__ nbr, int* __restrict__ deg){
  int row = blockIdx.x * 4 + (threadIdx.x >> 6);
  int lane = threadIdx.x & 63;
  if (row >= Nn) return;
  const float* ar = adj + (size_t)row * Nn;
  int cnt = 0;
  for (int base = 0; base < Nn; base += 64){
    int c = base + lane;
    bool nz = (c < Nn) && (ar[c] > 0.f);
    unsigned long long m = __ballot(nz);
    if (nz){
      int pos = cnt + __popcll(m & ((1ULL << lane) - 1ULL));
      if (pos < MAXN) nbr[(size_t)row * MAXN + pos] = c;
    }
    cnt += __popcll(m);
  }
  if (lane == 0) deg[row] = (cnt > MAXN) ? MAXN : cnt;
}

// ---------------------------------------------------------------- G1: h = (x*scale) @ W ; f1 = h.a[:64]; f2 = h.a[64:]
__global__ __launch_bounds__(256) void gat_xw(const float* __restrict__ x, float scale,
                                              const float* __restrict__ W,
                                              const float* __restrict__ avec,
                                              float* __restrict__ hmat,
                                              float* __restrict__ f1, float* __restrict__ f2){
  __shared__ float Ws[64][64];
  __shared__ float as_[128];
  __shared__ float xs[4][64];
  int tid = threadIdx.x, lane = tid & 63, wid = tid >> 6;
  for (int i = tid; i < 4096; i += 256) Ws[i >> 6][i & 63] = W[i];
  if (tid < 128) as_[tid] = avec[tid];
  __syncthreads();
  int row = blockIdx.x * 4 + wid;
  xs[wid][lane] = x[(size_t)row * 64 + lane] * scale;
  float acc = 0.f;
  #pragma unroll
  for (int k = 0; k < 64; k++) acc += xs[wid][k] * Ws[k][lane];
  float p1 = wredsum(acc * as_[lane]);
  float p2 = wredsum(acc * as_[64 + lane]);
  hmat[(size_t)row * 64 + lane] = acc;
  if (lane == 0){ f1[row] = p1; f2[row] = p2; }
}

// ---------------------------------------------------------------- G2: sparse masked softmax + aggregate + elu
__global__ __launch_bounds__(256) void gat_att(const float* __restrict__ hmat,
                                               const float* __restrict__ f1,
                                               const float* __restrict__ f2,
                                               const int* __restrict__ nbr,
                                               const int* __restrict__ deg,
                                               float* __restrict__ outp, int accum){
  __shared__ int nbs[4][MAXN];
  __shared__ float attb[4][MAXN];
  int tid = threadIdx.x, lane = tid & 63, w = tid >> 6;
  int row = blockIdx.x * 4 + w;
  int d = deg[row];
  float fr = f1[row];
  float mx = -3.0e38f;
  for (int j = lane; j < d; j += 64){
    int c = nbr[(size_t)row * MAXN + j];
    nbs[w][j] = c;
    float e = fr + f2[c];
    e = (e >= 0.f) ? e : 0.2f * e;   // leaky_relu alpha=0.2
    attb[w][j] = e;
    mx = fmaxf(mx, e);
  }
  mx = wredmax(mx);
  float sum = 0.f;
  for (int j = lane; j < d; j += 64){
    float ex = __expf(attb[w][j] - mx);
    attb[w][j] = ex;
    sum += ex;
  }
  sum = wredsum(sum);
  float inv = 1.f / sum;
  float acc = 0.f;
  for (int j = 0; j < d; j++)
    acc += attb[w][j] * hmat[(size_t)nbs[w][j] * 64 + lane];
  acc *= inv;
  acc = (acc > 0.f) ? acc : expm1f(acc);   // elu
  if (accum) outp[(size_t)row * 64 + lane] += acc;
  else       outp[(size_t)row * 64 + lane] = acc;
}

// ---------------------------------------------------------------- K5: feature concat + FC + loss write
__global__ void final_fc(const float* __restrict__ matrix_ans,
                         const float* __restrict__ hfin1, const float* __restrict__ hfin2,
                         const float* __restrict__ gat_emb,
                         const int* __restrict__ u1, const int* __restrict__ u2,
                         const float* __restrict__ fc_w, const float* __restrict__ fc_b,
                         const float* __restrict__ perb, float* __restrict__ out){
  int b = blockIdx.x, lane = threadIdx.x;  // 64 threads
  int a = u1[b], c = u2[b];
  float acc0 = 0.f, acc1 = 0.f;
  for (int i = lane; i < 592; i += 64){
    float f;
    if (i < 400) f = matrix_ans[(size_t)b * 400 + i];
    else if (i < 528){
      int d = i - 400;
      f = tanhf(hfin1[(size_t)b * 128 + d] * hfin2[(size_t)b * 128 + d]);
    } else {
      int d = i - 528;
      f = tanhf(gat_emb[(size_t)a * 64 + d] * gat_emb[(size_t)c * 64 + d]);
    }
    acc0 += f * fc_w[i];
    acc1 += f * fc_w[592 + i];
  }
  acc0 = wredsum(acc0);
  acc1 = wredsum(acc1);
  if (lane == 0){
    out[b * 2]     = acc0 + fc_b[0];
    out[b * 2 + 1] = acc1 + fc_b[1];
  }
  if (b == 0){
    float ls = 0.f;
    for (int i = lane; i < 256; i += 64) ls += perb[i];
    ls = wredsum(ls);
    if (lane == 0) out[512] = -ls / 256.f;
  }
}

// ----------------------------------------------------------------
extern "C" void kernel_launch(void* const* d_in, const int* in_sizes, int n_in,
                              void* d_out, int out_size, void* d_ws, size_t ws_size,
                              hipStream_t stream){
  (void)in_sizes; (void)n_in; (void)out_size; (void)ws_size;
  const int*   u1       = (const int*)  d_in[0];
  const int*   u2       = (const int*)  d_in[1];
  const int*   len1     = (const int*)  d_in[2];
  const int*   len2     = (const int*)  d_in[3];
  const int*   loc1     = (const int*)  d_in[4];
  const int*   loc2     = (const int*)  d_in[5];
  const int*   time1    = (const int*)  d_in[6];
  const int*   time2    = (const int*)  d_in[7];
  const float* tg1      = (const float*)d_in[8];
  const float* tg2      = (const float*)d_in[9];
  const float* loc_emb  = (const float*)d_in[10];
  const float* time_emb = (const float*)d_in[11];
  const float* user_emb = (const float*)d_in[12];
  const float* gat_W    = (const float*)d_in[13];
  const float* gat_a    = (const float*)d_in[14];
  const float* gat_Wout = (const float*)d_in[15];
  const float* gat_aout = (const float*)d_in[16];
  const float* adj      = (const float*)d_in[17];
  const float* Wih      = (const float*)d_in[18];
  const float* Whh      = (const float*)d_in[19];
  const float* bih      = (const float*)d_in[20];
  const float* bhh      = (const float*)d_in[21];
  const float* time_v   = (const float*)d_in[22];
  const float* time_w   = (const float*)d_in[23];
  const float* time_b   = (const float*)d_in[24];
  const float* fc_w     = (const float*)d_in[25];
  const float* fc_b     = (const float*)d_in[26];
  float* out = (float*)d_out;

  size_t off = 0;
  auto alloc = [&](size_t nbytes) -> void* {
    void* p = (char*)d_ws + off;
    off += (nbytes + 255) & ~(size_t)255;
    return p;
  };
  float* ne1        = (float*)alloc((size_t)Bb * Ss * Ee * 4);
  float* ne2        = (float*)alloc((size_t)Bb * Ss * Ee * 4);
  float* matrix_ans = (float*)alloc((size_t)Bb * 400 * 4);
  float* xgtab      = (float*)alloc((size_t)168 * 512 * 4);
  float* hfin1      = (float*)alloc((size_t)Bb * Hh * 4);
  float* hfin2      = (float*)alloc((size_t)Bb * Hh * 4);
  float* gat_h      = (float*)alloc((size_t)Nn * 64 * 4);
  float* gat_acc    = (float*)alloc((size_t)Nn * 64 * 4);
  float* gat_emb    = (float*)alloc((size_t)Nn * 64 * 4);
  float* f1w        = (float*)alloc((size_t)Nn * 4);
  float* f2w        = (float*)alloc((size_t)Nn * 4);
  float* perb       = (float*)alloc((size_t)Bb * 4);
  int*   nbr        = (int*)  alloc((size_t)Nn * MAXN * 4);
  int*   deg        = (int*)  alloc((size_t)Nn * 4);

  // cosine-sim branch
  norm_gather<<<(2 * Bb * Ss) / 4, 256, 0, stream>>>(loc_emb, loc1, loc2, ne1, ne2);
  cosmax_kernel<<<Bb, 256, 0, stream>>>(ne1, ne2, len1, len2, matrix_ans);

  // LSTM branch (time-loss fused; only final hidden rows + perb leave the kernel)
  xg_table<<<168, 512, 0, stream>>>(time_emb, Wih, bih, bhh, xgtab);
  lstm_kernel<<<Bb, 512, 0, stream>>>(xgtab, time1, time2, Whh, tg1, tg2, len1, len2,
                                      time_v, time_w, time_b, hfin1, hfin2, perb);

  // GAT branch (sparse: softmax over non-edges underflows to exactly 0 in fp32)
  build_csr<<<Nn / 4, 256, 0, stream>>>(adj, nbr, deg);
  for (int hd = 0; hd < 3; hd++){
    gat_xw<<<Nn / 4, 256, 0, stream>>>(user_emb, 1.f, gat_W + (size_t)hd * 64 * 64,
                                       gat_a + (size_t)hd * 128, gat_h, f1w, f2w);
    gat_att<<<Nn / 4, 256, 0, stream>>>(gat_h, f1w, f2w, nbr, deg, gat_acc, hd == 0 ? 0 : 1);
  }
  gat_xw<<<Nn / 4, 256, 0, stream>>>(gat_acc, 1.f / 3.f, gat_Wout, gat_aout, gat_h, f1w, f2w);
  gat_att<<<Nn / 4, 256, 0, stream>>>(gat_h, f1w, f2w, nbr, deg, gat_emb, 0);

  // fuse + FC + loss
  final_fc<<<Bb, 64, 0, stream>>>(matrix_ans, hfin1, hfin2, gat_emb,
                                  u1, u2, fc_w, fc_b, perb, out);
}